// Round 1
// baseline (1183.646 us; speedup 1.0000x reference)
//
#include <hip/hip_runtime.h>
#include <math.h>

#define N_NODES 10000
#define N_EDGES 64000
#define H 128
#define L 8
#define NL (N_NODES * L)

__device__ __forceinline__ float silu_f(float x) { return x / (1.f + __expf(-x)); }

// ---------------- LayerNorm: one wave per node ----------------
__global__ __launch_bounds__(256) void ln_kernel(const float* __restrict__ x,
                                                 const float* __restrict__ g,
                                                 const float* __restrict__ b,
                                                 float* __restrict__ out, int n_nodes) {
  int wave = threadIdx.x >> 6;
  int lane = threadIdx.x & 63;
  int n = blockIdx.x * 4 + wave;
  if (n >= n_nodes) return;
  const float* xr = x + (size_t)n * H;
  float a0 = xr[lane], a1 = xr[lane + 64];
  float s = a0 + a1;
#pragma unroll
  for (int off = 32; off >= 1; off >>= 1) s += __shfl_xor(s, off, 64);
  float mu = s * (1.f / H);
  float d0 = a0 - mu, d1 = a1 - mu;
  float v = d0 * d0 + d1 * d1;
#pragma unroll
  for (int off = 32; off >= 1; off >>= 1) v += __shfl_xor(v, off, 64);
  float rstd = rsqrtf(v * (1.f / H) + 1e-5f);
  float* orow = out + (size_t)n * H;
  orow[lane] = d0 * rstd * g[lane] + b[lane];
  orow[lane + 64] = d1 * rstd * g[lane + 64] + b[lane + 64];
}

// ---------------- vec * vln_w elementwise ----------------
__global__ __launch_bounds__(256) void vecw_kernel(const float* __restrict__ vec,
                                                   const float* __restrict__ w,
                                                   float* __restrict__ out, size_t total) {
  size_t i = (size_t)blockIdx.x * blockDim.x + threadIdx.x;
  size_t stride = (size_t)gridDim.x * blockDim.x;
  for (; i < total; i += stride) out[i] = vec[i] * w[i & 127];
}

// ---------------- generic f32 GEMM: C = act(A @ B[:,bcol:bcol+Nn] + bias) ----------------
// A: [M,K] row-major (lda=K), B row-major with leading dim ldb, C: [M,Nn] contiguous.
#define TS 64
#define TK 16
__global__ __launch_bounds__(256) void gemm_f32(const float* __restrict__ A,
                                                const float* __restrict__ B,
                                                const float* __restrict__ bias,
                                                float* __restrict__ C, int M, int Nn, int K,
                                                int ldb, int bcol, int act) {
  __shared__ float As[TK][TS + 1];
  __shared__ float Bs[TK][TS + 1];
  int tx = threadIdx.x & 15;
  int ty = threadIdx.x >> 4;
  int row0 = blockIdx.y * TS, col0 = blockIdx.x * TS;
  float acc[4][4] = {};
  for (int kk = 0; kk < K; kk += TK) {
    for (int i = threadIdx.x; i < TS * TK; i += 256) {
      int m = i >> 4, k = i & 15;
      int gm = row0 + m;
      As[k][m] = (gm < M) ? A[(size_t)gm * K + kk + k] : 0.f;
    }
    for (int i = threadIdx.x; i < TS * TK; i += 256) {
      int k = i >> 6, n = i & 63;
      int gn = col0 + n;
      Bs[k][n] = (gn < Nn) ? B[(size_t)(kk + k) * ldb + bcol + gn] : 0.f;
    }
    __syncthreads();
#pragma unroll
    for (int k = 0; k < TK; ++k) {
      float a[4], bb[4];
#pragma unroll
      for (int i = 0; i < 4; i++) a[i] = As[k][ty * 4 + i];
#pragma unroll
      for (int j = 0; j < 4; j++) bb[j] = Bs[k][tx * 4 + j];
#pragma unroll
      for (int i = 0; i < 4; i++)
#pragma unroll
        for (int j = 0; j < 4; j++) acc[i][j] += a[i] * bb[j];
    }
    __syncthreads();
  }
#pragma unroll
  for (int i = 0; i < 4; i++) {
    int gm = row0 + ty * 4 + i;
    if (gm >= M) continue;
#pragma unroll
    for (int j = 0; j < 4; j++) {
      int gn = col0 + tx * 4 + j;
      if (gn >= Nn) continue;
      float xv = acc[i][j] + (bias ? bias[bcol + gn] : 0.f);
      if (act == 1) xv = xv / (1.f + __expf(-xv));
      C[(size_t)gm * Nn + gn] = xv;
    }
  }
}

// ---------------- vec_dot reduce: Σ_l vec1*vec2 ----------------
__global__ __launch_bounds__(256) void vecdot_kernel(const float* __restrict__ t12,
                                                     float* __restrict__ vdot, int n_nodes) {
  int n = blockIdx.x * 2 + (threadIdx.x >> 7);
  int h = threadIdx.x & 127;
  if (n >= n_nodes) return;
  const float* base = t12 + (size_t)n * 8 * 256;
  float acc = 0.f;
#pragma unroll
  for (int l = 0; l < 8; l++) acc += base[l * 256 + h] * base[l * 256 + 128 + h];
  vdot[(size_t)n * H + h] = acc;
}

// ---------------- message: attn + vm per edge ----------------
__global__ __launch_bounds__(256) void msg_kernel(const float* __restrict__ q,
                                                  const float* __restrict__ k,
                                                  const float* __restrict__ v,
                                                  const float* __restrict__ dk,
                                                  const float* __restrict__ dv,
                                                  const float* __restrict__ r_ij,
                                                  const int* __restrict__ ei,
                                                  float* __restrict__ vm) {
  int e = blockIdx.x * 2 + (threadIdx.x >> 7);
  int h = threadIdx.x & 127;
  int src = ei[e], dst = ei[N_EDGES + e];
  float t = q[(size_t)dst * H + h] * k[(size_t)src * H + h] * dk[(size_t)e * H + h];
#pragma unroll
  for (int off = 8; off >= 1; off >>= 1) t += __shfl_xor(t, off, 16);
  float r = r_ij[e];
  float cut = 0.5f * (__cosf(0.6283185307f * r) + 1.f);
  cut = (r < 5.f) ? cut : 0.f;
  float attn = silu_f(t) * cut;
  vm[(size_t)e * H + h] = v[(size_t)src * H + h] * dv[(size_t)e * H + h] * attn;
}

// ---------------- scatter: x_agg += vm ; dvec += vec_m ----------------
__global__ __launch_bounds__(256) void scatter_kernel(const float* __restrict__ vm,
                                                      const float* __restrict__ s,
                                                      const float* __restrict__ vecw,
                                                      const float* __restrict__ d_ij,
                                                      const int* __restrict__ ei,
                                                      float* __restrict__ x_agg,
                                                      float* __restrict__ dvec) {
  int e = blockIdx.x * 2 + (threadIdx.x >> 7);
  int h = threadIdx.x & 127;
  int src = ei[e], dst = ei[N_EDGES + e];
  atomicAdd(&x_agg[(size_t)dst * H + h], vm[(size_t)e * H + h]);
  float s1 = s[(size_t)e * 256 + h];
  float s2 = s[(size_t)e * 256 + 128 + h];
  const float* vrow = vecw + (size_t)src * L * H + h;
  float* drow = dvec + (size_t)dst * L * H + h;
#pragma unroll
  for (int l = 0; l < L; l++) {
    float val = vrow[l * H] * s1 + s2 * d_ij[(size_t)e * L + l];
    atomicAdd(&drow[l * H], val);
  }
}

// ---------------- edge update: df = silu(f@W_f+b)*w_dot ----------------
// w_dot = Σ_l vt·vs − p1·p2·(2 − Σ_l d²) with p1=Σ vt·d, p2=Σ vs·d
__global__ __launch_bounds__(256) void edgeupd_kernel(const float* __restrict__ vt,
                                                      const float* __restrict__ vs,
                                                      const float* __restrict__ d_ij,
                                                      const float* __restrict__ dfw,
                                                      const int* __restrict__ ei,
                                                      float* __restrict__ df) {
  int e = blockIdx.x * 2 + (threadIdx.x >> 7);
  int h = threadIdx.x & 127;
  int src = ei[e], dst = ei[N_EDGES + e];
  float d[L];
  float sd2 = 0.f;
#pragma unroll
  for (int l = 0; l < L; l++) {
    d[l] = d_ij[(size_t)e * L + l];
    sd2 += d[l] * d[l];
  }
  const float* arow = vt + (size_t)dst * L * H + h;
  const float* brow = vs + (size_t)src * L * H + h;
  float dot = 0.f, p1 = 0.f, p2 = 0.f;
#pragma unroll
  for (int l = 0; l < L; l++) {
    float a = arow[l * H], bb = brow[l * H];
    dot += a * bb;
    p1 += a * d[l];
    p2 += bb * d[l];
  }
  float wdot = dot - p1 * p2 * (2.f - sd2);
  df[(size_t)e * H + h] = dfw[(size_t)e * H + h] * wdot;
}

// ---------------- final node update ----------------
__global__ __launch_bounds__(256) void final_kernel(const float* __restrict__ o,
                                                    const float* __restrict__ vdot,
                                                    const float* __restrict__ vec3,
                                                    float* __restrict__ dx,
                                                    float* __restrict__ dvec, int n_nodes) {
  int n = blockIdx.x * 2 + (threadIdx.x >> 7);
  int h = threadIdx.x & 127;
  if (n >= n_nodes) return;
  float o1 = o[(size_t)n * 384 + h];
  float o2 = o[(size_t)n * 384 + 128 + h];
  float o3 = o[(size_t)n * 384 + 256 + h];
  dx[(size_t)n * H + h] = vdot[(size_t)n * H + h] * o2 + o3;
  float* drow = dvec + (size_t)n * L * H + h;
  const float* v3 = vec3 + (size_t)n * L * H + h;
#pragma unroll
  for (int l = 0; l < L; l++) drow[l * H] += v3[l * H] * o1;
}

extern "C" void kernel_launch(void* const* d_in, const int* in_sizes, int n_in, void* d_out,
                              int out_size, void* d_ws, size_t ws_size, hipStream_t stream) {
  const float* x = (const float*)d_in[0];
  const float* vec = (const float*)d_in[1];
  const float* f_ij = (const float*)d_in[2];
  const float* d_ij = (const float*)d_in[3];
  const float* r_ij = (const float*)d_in[4];
  const int* ei = (const int*)d_in[5];
  const float* ln_g = (const float*)d_in[6];
  const float* ln_b = (const float*)d_in[7];
  const float* vln_w = (const float*)d_in[8];
  const float* W_vec = (const float*)d_in[9];
  const float* W_q = (const float*)d_in[10];
  const float* b_q = (const float*)d_in[11];
  const float* W_k = (const float*)d_in[12];
  const float* b_k = (const float*)d_in[13];
  const float* W_v = (const float*)d_in[14];
  const float* b_v = (const float*)d_in[15];
  const float* W_dk = (const float*)d_in[16];
  const float* b_dk = (const float*)d_in[17];
  const float* W_dv = (const float*)d_in[18];
  const float* b_dv = (const float*)d_in[19];
  const float* W_s = (const float*)d_in[20];
  const float* b_s = (const float*)d_in[21];
  const float* W_f = (const float*)d_in[22];
  const float* b_f = (const float*)d_in[23];
  const float* W_src = (const float*)d_in[24];
  const float* W_trg = (const float*)d_in[25];
  const float* W_o = (const float*)d_in[26];
  const float* b_o = (const float*)d_in[27];

  float* out = (float*)d_out;
  float* dx = out;
  float* dvec = out + (size_t)N_NODES * H;
  float* df = dvec + (size_t)N_NODES * L * H;

  float* ws = (float*)d_ws;
  float* xln = ws;                 // 1,280,000 floats (reused as x_agg)
  float* q = ws + 1280000;         // 1,280,000
  float* kbuf = ws + 2560000;      // 1,280,000
  float* vbuf = ws + 3840000;      // 1,280,000
  float* vecw = ws + 5120000;      // 10,240,000
  float* vec3 = ws + 15360000;     // 10,240,000
  float* vdot = ws + 25600000;     // 1,280,000
  float* R = ws + 26880000;        // 20,480,000 (tmp12 -> dk|dv -> vt|vs)
  float* vmb = ws + 47360000;      // 8,192,000 (vm -> dfw)
  float* S = ws + 55552000;        // 16,384,000 (s -> o)
  // total: 71,936,000 floats = 287.7 MB

  float* t12 = R;
  float* dk = R;
  float* dv = R + 8192000;
  float* vt = R;
  float* vs = R + 10240000;
  float* x_agg = xln;
  float* dfw = vmb;
  float* o_buf = S;

  dim3 b256(256);

  // 1. x_ln = layernorm(x)
  ln_kernel<<<dim3((N_NODES + 3) / 4), b256, 0, stream>>>(x, ln_g, ln_b, xln, N_NODES);
  // 2. vecw = vec * vln_w
  vecw_kernel<<<dim3(2048), b256, 0, stream>>>(vec, vln_w, vecw, (size_t)N_NODES * L * H);
  // 3. tmp12 = vecw @ W_vec[:, 0:256]
  gemm_f32<<<dim3(4, 1250), b256, 0, stream>>>(vecw, W_vec, nullptr, t12, NL, 256, 128, 384, 0, 0);
  // 4. vec3 = vecw @ W_vec[:, 256:384]
  gemm_f32<<<dim3(2, 1250), b256, 0, stream>>>(vecw, W_vec, nullptr, vec3, NL, 128, 128, 384, 256, 0);
  // 5. vec_dot = Σ_l vec1*vec2
  vecdot_kernel<<<dim3(5000), b256, 0, stream>>>(t12, vdot, N_NODES);
  // 6. q,k,v
  gemm_f32<<<dim3(2, 157), b256, 0, stream>>>(xln, W_q, b_q, q, N_NODES, 128, 128, 128, 0, 0);
  gemm_f32<<<dim3(2, 157), b256, 0, stream>>>(xln, W_k, b_k, kbuf, N_NODES, 128, 128, 128, 0, 0);
  gemm_f32<<<dim3(2, 157), b256, 0, stream>>>(xln, W_v, b_v, vbuf, N_NODES, 128, 128, 128, 0, 0);
  // 7. dk, dv (silu)
  gemm_f32<<<dim3(2, 1000), b256, 0, stream>>>(f_ij, W_dk, b_dk, dk, N_EDGES, 128, 128, 128, 0, 1);
  gemm_f32<<<dim3(2, 1000), b256, 0, stream>>>(f_ij, W_dv, b_dv, dv, N_EDGES, 128, 128, 128, 0, 1);
  // 8. zero accumulators (x_agg reuses xln region - after qkv GEMMs)
  hipMemsetAsync(x_agg, 0, (size_t)N_NODES * H * sizeof(float), stream);
  hipMemsetAsync(dvec, 0, (size_t)N_NODES * L * H * sizeof(float), stream);
  // 9. message -> vm
  msg_kernel<<<dim3(N_EDGES / 2), b256, 0, stream>>>(q, kbuf, vbuf, dk, dv, r_ij, ei, vmb);
  // 10. s = silu(vm @ W_s + b_s)
  gemm_f32<<<dim3(4, 1000), b256, 0, stream>>>(vmb, W_s, b_s, S, N_EDGES, 256, 128, 256, 0, 1);
  // 11. scatter-add into x_agg and dvec
  scatter_kernel<<<dim3(N_EDGES / 2), b256, 0, stream>>>(vmb, S, vecw, d_ij, ei, x_agg, dvec);
  // 12. vt = vecw @ W_trg ; vs = vecw @ W_src
  gemm_f32<<<dim3(2, 1250), b256, 0, stream>>>(vecw, W_trg, nullptr, vt, NL, 128, 128, 128, 0, 0);
  gemm_f32<<<dim3(2, 1250), b256, 0, stream>>>(vecw, W_src, nullptr, vs, NL, 128, 128, 128, 0, 0);
  // 13. dfw = silu(f_ij @ W_f + b_f)
  gemm_f32<<<dim3(2, 1000), b256, 0, stream>>>(f_ij, W_f, b_f, dfw, N_EDGES, 128, 128, 128, 0, 1);
  // 14. edge update -> df output
  edgeupd_kernel<<<dim3(N_EDGES / 2), b256, 0, stream>>>(vt, vs, d_ij, dfw, ei, df);
  // 15. o = x_agg @ W_o + b_o
  gemm_f32<<<dim3(6, 157), b256, 0, stream>>>(x_agg, W_o, b_o, o_buf, N_NODES, 384, 128, 384, 0, 0);
  // 16. final: dx, dvec += vec3*o1
  final_kernel<<<dim3(5000), b256, 0, stream>>>(o_buf, vdot, vec3, dx, dvec, N_NODES);
}

// Round 2
// 712.687 us; speedup vs baseline: 1.6608x; 1.6608x over previous
//
#include <hip/hip_runtime.h>
#include <hip/hip_bf16.h>
#include <math.h>

#define N_NODES 10000
#define N_EDGES 64000
#define H 128
#define L 8
#define NL (N_NODES * L)

typedef __attribute__((ext_vector_type(4))) float f32x4;
typedef __attribute__((ext_vector_type(8))) __bf16 bf16x8;

__device__ __forceinline__ float silu_f(float x) { return x / (1.f + __expf(-x)); }

// ---------------- LayerNorm: one wave per node ----------------
__global__ __launch_bounds__(256) void ln_kernel(const float* __restrict__ x,
                                                 const float* __restrict__ g,
                                                 const float* __restrict__ b,
                                                 float* __restrict__ out, int n_nodes) {
  int wave = threadIdx.x >> 6;
  int lane = threadIdx.x & 63;
  int n = blockIdx.x * 4 + wave;
  if (n >= n_nodes) return;
  const float* xr = x + (size_t)n * H;
  float a0 = xr[lane], a1 = xr[lane + 64];
  float s = a0 + a1;
#pragma unroll
  for (int off = 32; off >= 1; off >>= 1) s += __shfl_xor(s, off, 64);
  float mu = s * (1.f / H);
  float d0 = a0 - mu, d1 = a1 - mu;
  float v = d0 * d0 + d1 * d1;
#pragma unroll
  for (int off = 32; off >= 1; off >>= 1) v += __shfl_xor(v, off, 64);
  float rstd = rsqrtf(v * (1.f / H) + 1e-5f);
  float* orow = out + (size_t)n * H;
  orow[lane] = d0 * rstd * g[lane] + b[lane];
  orow[lane + 64] = d1 * rstd * g[lane + 64] + b[lane + 64];
}

// ---------------- vec * vln_w elementwise ----------------
__global__ __launch_bounds__(256) void vecw_kernel(const float* __restrict__ vec,
                                                   const float* __restrict__ w,
                                                   float* __restrict__ out, size_t total) {
  size_t i = (size_t)blockIdx.x * blockDim.x + threadIdx.x;
  size_t stride = (size_t)gridDim.x * blockDim.x;
  for (; i < total; i += stride) out[i] = vec[i] * w[i & 127];
}

// ---------------- weight convert: f32 [128][nc] -> bf16 [nc][128], + bias concat ----------------
__global__ __launch_bounds__(256) void wconv_kernel(
    const float* __restrict__ Wvec, const float* __restrict__ Wq, const float* __restrict__ Wk,
    const float* __restrict__ Wv, const float* __restrict__ Wdk, const float* __restrict__ Wdv,
    const float* __restrict__ Ws, const float* __restrict__ Wtrg, const float* __restrict__ Wsrc,
    const float* __restrict__ Wf, const float* __restrict__ Wo,
    const float* __restrict__ bq, const float* __restrict__ bk, const float* __restrict__ bv,
    const float* __restrict__ bdk, const float* __restrict__ bdv,
    __bf16* __restrict__ Wt, float* __restrict__ bqkv, float* __restrict__ bdkdv) {
  int bid = blockIdx.x;
  int t = threadIdx.x;
  if (bid >= 256) {
    if (bid == 256) {
      if (t < 128) { bqkv[t] = bq[t]; bqkv[128 + t] = bk[t]; bqkv[256 + t] = bv[t]; }
    } else {
      if (t < 128) { bdkdv[t] = bdk[t]; bdkdv[128 + t] = bdv[t]; }
    }
    return;
  }
  const float* W; int ldw, dst, tb;
  if      (bid < 48)  { W = Wvec; ldw = 384; dst = 0;      tb = 0;   }
  else if (bid < 64)  { W = Wq;   ldw = 128; dst = 49152;  tb = 48;  }
  else if (bid < 80)  { W = Wk;   ldw = 128; dst = 65536;  tb = 64;  }
  else if (bid < 96)  { W = Wv;   ldw = 128; dst = 81920;  tb = 80;  }
  else if (bid < 112) { W = Wdk;  ldw = 128; dst = 98304;  tb = 96;  }
  else if (bid < 128) { W = Wdv;  ldw = 128; dst = 114688; tb = 112; }
  else if (bid < 160) { W = Ws;   ldw = 256; dst = 131072; tb = 128; }
  else if (bid < 176) { W = Wtrg; ldw = 128; dst = 163840; tb = 160; }
  else if (bid < 192) { W = Wsrc; ldw = 128; dst = 180224; tb = 176; }
  else if (bid < 208) { W = Wf;   ldw = 128; dst = 196608; tb = 192; }
  else                { W = Wo;   ldw = 384; dst = 212992; tb = 208; }
  int lt = bid - tb;
  int ctiles = ldw >> 5;
  int kt = lt / ctiles, ct = lt % ctiles;
  __shared__ float tile[32][33];
  int tx = t & 31, ty = t >> 5;
#pragma unroll
  for (int i = 0; i < 4; ++i)
    tile[ty + i * 8][tx] = W[(size_t)(kt * 32 + ty + i * 8) * ldw + ct * 32 + tx];
  __syncthreads();
#pragma unroll
  for (int i = 0; i < 4; ++i)
    Wt[dst + (size_t)(ct * 32 + ty + i * 8) * 128 + kt * 32 + tx] =
        (__bf16)tile[tx][ty + i * 8];
}

// ---------------- bf16 MFMA GEMM: C[M,Nn] = act(A[M,128] @ Bt^T + bias) ----------------
// A: f32 row-major [M][128]. Bt: bf16 [Nn][128] (k-contiguous). C: f32 [M][Nn].
__global__ __launch_bounds__(256) void gemm_bf16(const float* __restrict__ A,
                                                 const __bf16* __restrict__ Bt,
                                                 const float* __restrict__ bias,
                                                 float* __restrict__ C, int M, int Nn, int act) {
  __shared__ __bf16 As[128 * 128];
  __shared__ __bf16 Bs[128 * 128];
  const int tid = threadIdx.x;
  const int lane = tid & 63;
  const int wave = tid >> 6;
  const int wm = wave >> 1, wn = wave & 1;
  const int row0 = blockIdx.x * 128;

  // stage A: f32 -> bf16, XOR-swizzled (G4: break the 256B row stride)
#pragma unroll
  for (int i = 0; i < 8; ++i) {
    int c = tid + i * 256;
    int row = c >> 4, k8 = c & 15;
    int gm = row0 + row;
    f32x4 f0 = {0.f, 0.f, 0.f, 0.f}, f1 = {0.f, 0.f, 0.f, 0.f};
    if (gm < M) {
      f0 = *(const f32x4*)(A + (size_t)gm * 128 + k8 * 8);
      f1 = *(const f32x4*)(A + (size_t)gm * 128 + k8 * 8 + 4);
    }
    bf16x8 h;
    h[0] = (__bf16)f0[0]; h[1] = (__bf16)f0[1]; h[2] = (__bf16)f0[2]; h[3] = (__bf16)f0[3];
    h[4] = (__bf16)f1[0]; h[5] = (__bf16)f1[1]; h[6] = (__bf16)f1[2]; h[7] = (__bf16)f1[3];
    int byte = (row * 256 + k8 * 16) ^ ((row & 7) << 4);
    *(bf16x8*)(As + (byte >> 1)) = h;
  }

  const int ncTiles = Nn >> 7;
  for (int ct = 0; ct < ncTiles; ++ct) {
    __syncthreads();  // As ready / previous Bs reads done
#pragma unroll
    for (int i = 0; i < 8; ++i) {
      int c = tid + i * 256;
      int n = c >> 4, k8 = c & 15;
      bf16x8 h = *(const bf16x8*)(Bt + ((size_t)(ct * 128 + n) << 7) + k8 * 8);
      int byte = (n * 256 + k8 * 16) ^ ((n & 7) << 4);
      *(bf16x8*)(Bs + (byte >> 1)) = h;
    }
    __syncthreads();

    f32x4 acc[4][4] = {};
#pragma unroll
    for (int ks = 0; ks < 4; ++ks) {
      bf16x8 a[4], b[4];
#pragma unroll
      for (int mi = 0; mi < 4; ++mi) {
        int row = wm * 64 + mi * 16 + (lane & 15);
        int byte = (row * 256 + ks * 64 + ((lane >> 4) << 4)) ^ ((row & 7) << 4);
        a[mi] = *(const bf16x8*)(As + (byte >> 1));
      }
#pragma unroll
      for (int ni = 0; ni < 4; ++ni) {
        int n = wn * 64 + ni * 16 + (lane & 15);
        int byte = (n * 256 + ks * 64 + ((lane >> 4) << 4)) ^ ((n & 7) << 4);
        b[ni] = *(const bf16x8*)(Bs + (byte >> 1));
      }
#pragma unroll
      for (int mi = 0; mi < 4; ++mi)
#pragma unroll
        for (int ni = 0; ni < 4; ++ni)
          acc[mi][ni] =
              __builtin_amdgcn_mfma_f32_16x16x32_bf16(a[mi], b[ni], acc[mi][ni], 0, 0, 0);
    }

    // epilogue: C/D layout col=lane&15, row=(lane>>4)*4+reg  [m89]
#pragma unroll
    for (int mi = 0; mi < 4; ++mi) {
      int rbase = row0 + wm * 64 + mi * 16 + ((lane >> 4) << 2);
#pragma unroll
      for (int ni = 0; ni < 4; ++ni) {
        int gcol = ct * 128 + wn * 64 + ni * 16 + (lane & 15);
        float bv = bias ? bias[gcol] : 0.f;
#pragma unroll
        for (int r = 0; r < 4; ++r) {
          int grow = rbase + r;
          if (grow < M) {
            float xv = acc[mi][ni][r] + bv;
            if (act) xv = silu_f(xv);
            C[(size_t)grow * Nn + gcol] = xv;
          }
        }
      }
    }
  }
}

// ---------------- vec_dot reduce: Σ_l vec1*vec2 (t12: [NL][256]) ----------------
__global__ __launch_bounds__(256) void vecdot_kernel(const float* __restrict__ t12,
                                                     float* __restrict__ vdot, int n_nodes) {
  int n = blockIdx.x * 2 + (threadIdx.x >> 7);
  int h = threadIdx.x & 127;
  if (n >= n_nodes) return;
  const float* base = t12 + (size_t)n * 8 * 256;
  float acc = 0.f;
#pragma unroll
  for (int l = 0; l < 8; l++) acc += base[l * 256 + h] * base[l * 256 + 128 + h];
  vdot[(size_t)n * H + h] = acc;
}

// ---------------- message: attn + vm per edge (qkv: [N][384], dkdv: [E][256]) ----------------
__global__ __launch_bounds__(256) void msg_kernel(const float* __restrict__ qkv,
                                                  const float* __restrict__ dkdv,
                                                  const float* __restrict__ r_ij,
                                                  const int* __restrict__ ei,
                                                  float* __restrict__ vm) {
  int e = blockIdx.x * 2 + (threadIdx.x >> 7);
  int h = threadIdx.x & 127;
  int src = ei[e], dst = ei[N_EDGES + e];
  float qv = qkv[(size_t)dst * 384 + h];
  float kv = qkv[(size_t)src * 384 + 128 + h];
  float vv = qkv[(size_t)src * 384 + 256 + h];
  float t = qv * kv * dkdv[(size_t)e * 256 + h];
#pragma unroll
  for (int off = 8; off >= 1; off >>= 1) t += __shfl_xor(t, off, 16);
  float r = r_ij[e];
  float cut = 0.5f * (__cosf(0.6283185307f * r) + 1.f);
  cut = (r < 5.f) ? cut : 0.f;
  float attn = silu_f(t) * cut;
  vm[(size_t)e * H + h] = vv * dkdv[(size_t)e * 256 + 128 + h] * attn;
}

// ---------------- scatter: x_agg += vm ; dvec += vec_m ----------------
__global__ __launch_bounds__(256) void scatter_kernel(const float* __restrict__ vm,
                                                      const float* __restrict__ s,
                                                      const float* __restrict__ vecw,
                                                      const float* __restrict__ d_ij,
                                                      const int* __restrict__ ei,
                                                      float* __restrict__ x_agg,
                                                      float* __restrict__ dvec) {
  int e = blockIdx.x * 2 + (threadIdx.x >> 7);
  int h = threadIdx.x & 127;
  int src = ei[e], dst = ei[N_EDGES + e];
  atomicAdd(&x_agg[(size_t)dst * H + h], vm[(size_t)e * H + h]);
  float s1 = s[(size_t)e * 256 + h];
  float s2 = s[(size_t)e * 256 + 128 + h];
  const float* vrow = vecw + (size_t)src * L * H + h;
  float* drow = dvec + (size_t)dst * L * H + h;
#pragma unroll
  for (int l = 0; l < L; l++) {
    float val = vrow[l * H] * s1 + s2 * d_ij[(size_t)e * L + l];
    atomicAdd(&drow[l * H], val);
  }
}

// ---------------- edge update (vtvs: [NL][256] = vt|vs) ----------------
__global__ __launch_bounds__(256) void edgeupd_kernel(const float* __restrict__ vtvs,
                                                      const float* __restrict__ d_ij,
                                                      const float* __restrict__ dfw,
                                                      const int* __restrict__ ei,
                                                      float* __restrict__ df) {
  int e = blockIdx.x * 2 + (threadIdx.x >> 7);
  int h = threadIdx.x & 127;
  int src = ei[e], dst = ei[N_EDGES + e];
  float d[L];
  float sd2 = 0.f;
#pragma unroll
  for (int l = 0; l < L; l++) {
    d[l] = d_ij[(size_t)e * L + l];
    sd2 += d[l] * d[l];
  }
  const float* arow = vtvs + (size_t)dst * L * 256 + h;
  const float* brow = vtvs + (size_t)src * L * 256 + 128 + h;
  float dot = 0.f, p1 = 0.f, p2 = 0.f;
#pragma unroll
  for (int l = 0; l < L; l++) {
    float a = arow[l * 256], bb = brow[l * 256];
    dot += a * bb;
    p1 += a * d[l];
    p2 += bb * d[l];
  }
  float wdot = dot - p1 * p2 * (2.f - sd2);
  df[(size_t)e * H + h] = dfw[(size_t)e * H + h] * wdot;
}

// ---------------- final node update ----------------
__global__ __launch_bounds__(256) void final_kernel(const float* __restrict__ o,
                                                    const float* __restrict__ vdot,
                                                    const float* __restrict__ vec3,
                                                    float* __restrict__ dx,
                                                    float* __restrict__ dvec, int n_nodes) {
  int n = blockIdx.x * 2 + (threadIdx.x >> 7);
  int h = threadIdx.x & 127;
  if (n >= n_nodes) return;
  float o1 = o[(size_t)n * 384 + h];
  float o2 = o[(size_t)n * 384 + 128 + h];
  float o3 = o[(size_t)n * 384 + 256 + h];
  dx[(size_t)n * H + h] = vdot[(size_t)n * H + h] * o2 + o3;
  float* drow = dvec + (size_t)n * L * H + h;
  const float* v3 = vec3 + (size_t)n * L * H + h;
#pragma unroll
  for (int l = 0; l < L; l++) drow[l * H] += v3[l * H] * o1;
}

extern "C" void kernel_launch(void* const* d_in, const int* in_sizes, int n_in, void* d_out,
                              int out_size, void* d_ws, size_t ws_size, hipStream_t stream) {
  const float* x = (const float*)d_in[0];
  const float* vec = (const float*)d_in[1];
  const float* f_ij = (const float*)d_in[2];
  const float* d_ij = (const float*)d_in[3];
  const float* r_ij = (const float*)d_in[4];
  const int* ei = (const int*)d_in[5];
  const float* ln_g = (const float*)d_in[6];
  const float* ln_b = (const float*)d_in[7];
  const float* vln_w = (const float*)d_in[8];
  const float* W_vec = (const float*)d_in[9];
  const float* W_q = (const float*)d_in[10];
  const float* b_q = (const float*)d_in[11];
  const float* W_k = (const float*)d_in[12];
  const float* b_k = (const float*)d_in[13];
  const float* W_v = (const float*)d_in[14];
  const float* b_v = (const float*)d_in[15];
  const float* W_dk = (const float*)d_in[16];
  const float* b_dk = (const float*)d_in[17];
  const float* W_dv = (const float*)d_in[18];
  const float* b_dv = (const float*)d_in[19];
  const float* W_s = (const float*)d_in[20];
  const float* b_s = (const float*)d_in[21];
  const float* W_f = (const float*)d_in[22];
  const float* b_f = (const float*)d_in[23];
  const float* W_src = (const float*)d_in[24];
  const float* W_trg = (const float*)d_in[25];
  const float* W_o = (const float*)d_in[26];
  const float* b_o = (const float*)d_in[27];

  float* out = (float*)d_out;
  float* dx = out;
  float* dvec = out + (size_t)N_NODES * H;
  float* df = dvec + (size_t)N_NODES * L * H;

  // ---- workspace plan (272.9 MB, timeshared) ----
  float* ws = (float*)d_ws;
  float* E = ws;                       // 20,480,000: t12 -> qkv -> vtvs -> o
  float* Cg = ws + 20480000;           // 16,384,000: dkdv -> s
  float* vecw = ws + 36864000;         // 10,240,000
  float* vec3 = ws + 47104000;         // 10,240,000
  float* D = ws + 57344000;            //  8,192,000: vm -> dfw
  float* xln = ws + 65536000;          //  1,280,000: xln -> x_agg
  float* vdot = ws + 66816000;         //  1,280,000
  __bf16* Wt = (__bf16*)(ws + 68096000);  // 262,144 bf16
  float* bqkv = ws + 68096000 + 131072;   // 384
  float* bdkdv = bqkv + 384;              // 256

  float* t12 = E;
  float* qkv = E;
  float* vtvs = E;
  float* o_buf = E;
  float* dkdv = Cg;
  float* s_buf = Cg;
  float* vm = D;
  float* dfw = D;
  float* x_agg = xln;

  dim3 b256(256);

  // 0. weight convert/transpose + bias concat
  wconv_kernel<<<dim3(258), b256, 0, stream>>>(W_vec, W_q, W_k, W_v, W_dk, W_dv, W_s, W_trg,
                                               W_src, W_f, W_o, b_q, b_k, b_v, b_dk, b_dv, Wt,
                                               bqkv, bdkdv);
  // 1. x_ln = layernorm(x)
  ln_kernel<<<dim3((N_NODES + 3) / 4), b256, 0, stream>>>(x, ln_g, ln_b, xln, N_NODES);
  // 2. vecw = vec * vln_w
  vecw_kernel<<<dim3(2048), b256, 0, stream>>>(vec, vln_w, vecw, (size_t)N_NODES * L * H);
  // 3. t12 = vecw @ W_vec[:,0:256]
  gemm_bf16<<<dim3(625), b256, 0, stream>>>(vecw, Wt + 0, nullptr, t12, NL, 256, 0);
  // 4. vec3 = vecw @ W_vec[:,256:384]
  gemm_bf16<<<dim3(625), b256, 0, stream>>>(vecw, Wt + 32768, nullptr, vec3, NL, 128, 0);
  // 5. vec_dot
  vecdot_kernel<<<dim3(5000), b256, 0, stream>>>(t12, vdot, N_NODES);
  // 6. qkv = xln @ [Wq|Wk|Wv] + b   (overwrites t12: consumed in 5)
  gemm_bf16<<<dim3(79), b256, 0, stream>>>(xln, Wt + 49152, bqkv, qkv, N_NODES, 384, 0);
  // 7. dkdv = silu(f_ij @ [Wdk|Wdv] + b)
  gemm_bf16<<<dim3(500), b256, 0, stream>>>(f_ij, Wt + 98304, bdkdv, dkdv, N_EDGES, 256, 1);
  // 8. zero accumulators (x_agg reuses xln — after qkv GEMM)
  hipMemsetAsync(x_agg, 0, (size_t)N_NODES * H * sizeof(float), stream);
  hipMemsetAsync(dvec, 0, (size_t)N_NODES * L * H * sizeof(float), stream);
  // 9. message -> vm
  msg_kernel<<<dim3(N_EDGES / 2), b256, 0, stream>>>(qkv, dkdv, r_ij, ei, vm);
  // 10. s = silu(vm @ W_s + b)   (overwrites dkdv: consumed in 9)
  gemm_bf16<<<dim3(500), b256, 0, stream>>>(vm, Wt + 131072, b_s, s_buf, N_EDGES, 256, 1);
  // 11. scatter-add into x_agg and dvec
  scatter_kernel<<<dim3(N_EDGES / 2), b256, 0, stream>>>(vm, s_buf, vecw, d_ij, ei, x_agg, dvec);
  // 12. vtvs = vecw @ [W_trg|W_src]   (overwrites qkv: consumed in 9)
  gemm_bf16<<<dim3(625), b256, 0, stream>>>(vecw, Wt + 163840, nullptr, vtvs, NL, 256, 0);
  // 13. dfw = silu(f_ij @ W_f + b)   (overwrites vm: consumed in 10,11)
  gemm_bf16<<<dim3(500), b256, 0, stream>>>(f_ij, Wt + 196608, b_f, dfw, N_EDGES, 128, 1);
  // 14. edge update -> df
  edgeupd_kernel<<<dim3(N_EDGES / 2), b256, 0, stream>>>(vtvs, d_ij, dfw, ei, df);
  // 15. o = x_agg @ W_o + b   (overwrites vtvs: consumed in 14)
  gemm_bf16<<<dim3(79), b256, 0, stream>>>(x_agg, Wt + 212992, b_o, o_buf, N_NODES, 384, 0);
  // 16. final: dx, dvec += vec3*o1
  final_kernel<<<dim3(5000), b256, 0, stream>>>(o_buf, vdot, vec3, dx, dvec, N_NODES);
}

// Round 3
// 567.411 us; speedup vs baseline: 2.0860x; 1.2560x over previous
//
#include <hip/hip_runtime.h>
#include <hip/hip_bf16.h>
#include <math.h>

#define N_NODES 10000
#define N_EDGES 64000
#define H 128
#define L 8
#define NL (N_NODES * L)

typedef __attribute__((ext_vector_type(4))) float f32x4;
typedef __attribute__((ext_vector_type(8))) __bf16 bf16x8;

__device__ __forceinline__ float silu_f(float x) { return x / (1.f + __expf(-x)); }

// ---------------- LayerNorm: one wave per node ----------------
__global__ __launch_bounds__(256) void ln_kernel(const float* __restrict__ x,
                                                 const float* __restrict__ g,
                                                 const float* __restrict__ b,
                                                 float* __restrict__ out, int n_nodes) {
  int wave = threadIdx.x >> 6;
  int lane = threadIdx.x & 63;
  int n = blockIdx.x * 4 + wave;
  if (n >= n_nodes) return;
  const float* xr = x + (size_t)n * H;
  float a0 = xr[lane], a1 = xr[lane + 64];
  float s = a0 + a1;
#pragma unroll
  for (int off = 32; off >= 1; off >>= 1) s += __shfl_xor(s, off, 64);
  float mu = s * (1.f / H);
  float d0 = a0 - mu, d1 = a1 - mu;
  float v = d0 * d0 + d1 * d1;
#pragma unroll
  for (int off = 32; off >= 1; off >>= 1) v += __shfl_xor(v, off, 64);
  float rstd = rsqrtf(v * (1.f / H) + 1e-5f);
  float* orow = out + (size_t)n * H;
  orow[lane] = d0 * rstd * g[lane] + b[lane];
  orow[lane + 64] = d1 * rstd * g[lane + 64] + b[lane + 64];
}

// ---------------- vec * vln_w elementwise ----------------
__global__ __launch_bounds__(256) void vecw_kernel(const float* __restrict__ vec,
                                                   const float* __restrict__ w,
                                                   float* __restrict__ out, size_t total) {
  size_t i = (size_t)blockIdx.x * blockDim.x + threadIdx.x;
  size_t stride = (size_t)gridDim.x * blockDim.x;
  for (; i < total; i += stride) out[i] = vec[i] * w[i & 127];
}

// ---------------- weight convert: f32 [128][nc] -> bf16 [nc][128], + bias concat ----------------
__global__ __launch_bounds__(256) void wconv_kernel(
    const float* __restrict__ Wvec, const float* __restrict__ Wq, const float* __restrict__ Wk,
    const float* __restrict__ Wv, const float* __restrict__ Wdk, const float* __restrict__ Wdv,
    const float* __restrict__ Ws, const float* __restrict__ Wtrg, const float* __restrict__ Wsrc,
    const float* __restrict__ Wf, const float* __restrict__ Wo,
    const float* __restrict__ bq, const float* __restrict__ bk, const float* __restrict__ bv,
    const float* __restrict__ bdk, const float* __restrict__ bdv,
    __bf16* __restrict__ Wt, float* __restrict__ bqkv, float* __restrict__ bdkdv) {
  int bid = blockIdx.x;
  int t = threadIdx.x;
  if (bid >= 256) {
    if (bid == 256) {
      if (t < 128) { bqkv[t] = bq[t]; bqkv[128 + t] = bk[t]; bqkv[256 + t] = bv[t]; }
    } else {
      if (t < 128) { bdkdv[t] = bdk[t]; bdkdv[128 + t] = bdv[t]; }
    }
    return;
  }
  const float* W; int ldw, dst, tb;
  if      (bid < 48)  { W = Wvec; ldw = 384; dst = 0;      tb = 0;   }
  else if (bid < 64)  { W = Wq;   ldw = 128; dst = 49152;  tb = 48;  }
  else if (bid < 80)  { W = Wk;   ldw = 128; dst = 65536;  tb = 64;  }
  else if (bid < 96)  { W = Wv;   ldw = 128; dst = 81920;  tb = 80;  }
  else if (bid < 112) { W = Wdk;  ldw = 128; dst = 98304;  tb = 96;  }
  else if (bid < 128) { W = Wdv;  ldw = 128; dst = 114688; tb = 112; }
  else if (bid < 160) { W = Ws;   ldw = 256; dst = 131072; tb = 128; }
  else if (bid < 176) { W = Wtrg; ldw = 128; dst = 163840; tb = 160; }
  else if (bid < 192) { W = Wsrc; ldw = 128; dst = 180224; tb = 176; }
  else if (bid < 208) { W = Wf;   ldw = 128; dst = 196608; tb = 192; }
  else                { W = Wo;   ldw = 384; dst = 212992; tb = 208; }
  int lt = bid - tb;
  int ctiles = ldw >> 5;
  int kt = lt / ctiles, ct = lt % ctiles;
  __shared__ float tile[32][33];
  int tx = t & 31, ty = t >> 5;
#pragma unroll
  for (int i = 0; i < 4; ++i)
    tile[ty + i * 8][tx] = W[(size_t)(kt * 32 + ty + i * 8) * ldw + ct * 32 + tx];
  __syncthreads();
#pragma unroll
  for (int i = 0; i < 4; ++i)
    Wt[dst + (size_t)(ct * 32 + ty + i * 8) * 128 + kt * 32 + tx] =
        (__bf16)tile[tx][ty + i * 8];
}

// ---------------- bf16 MFMA GEMM: C[M,Nn] = act(A[M,128] @ Bt^T + bias) ----------------
__global__ __launch_bounds__(256) void gemm_bf16(const float* __restrict__ A,
                                                 const __bf16* __restrict__ Bt,
                                                 const float* __restrict__ bias,
                                                 float* __restrict__ C, int M, int Nn, int act) {
  __shared__ __bf16 As[128 * 128];
  __shared__ __bf16 Bs[128 * 128];
  const int tid = threadIdx.x;
  const int lane = tid & 63;
  const int wave = tid >> 6;
  const int wm = wave >> 1, wn = wave & 1;
  const int row0 = blockIdx.x * 128;

#pragma unroll
  for (int i = 0; i < 8; ++i) {
    int c = tid + i * 256;
    int row = c >> 4, k8 = c & 15;
    int gm = row0 + row;
    f32x4 f0 = {0.f, 0.f, 0.f, 0.f}, f1 = {0.f, 0.f, 0.f, 0.f};
    if (gm < M) {
      f0 = *(const f32x4*)(A + (size_t)gm * 128 + k8 * 8);
      f1 = *(const f32x4*)(A + (size_t)gm * 128 + k8 * 8 + 4);
    }
    bf16x8 h;
    h[0] = (__bf16)f0[0]; h[1] = (__bf16)f0[1]; h[2] = (__bf16)f0[2]; h[3] = (__bf16)f0[3];
    h[4] = (__bf16)f1[0]; h[5] = (__bf16)f1[1]; h[6] = (__bf16)f1[2]; h[7] = (__bf16)f1[3];
    int byte = (row * 256 + k8 * 16) ^ ((row & 7) << 4);
    *(bf16x8*)(As + (byte >> 1)) = h;
  }

  const int ncTiles = Nn >> 7;
  for (int ct = 0; ct < ncTiles; ++ct) {
    __syncthreads();
#pragma unroll
    for (int i = 0; i < 8; ++i) {
      int c = tid + i * 256;
      int n = c >> 4, k8 = c & 15;
      bf16x8 h = *(const bf16x8*)(Bt + ((size_t)(ct * 128 + n) << 7) + k8 * 8);
      int byte = (n * 256 + k8 * 16) ^ ((n & 7) << 4);
      *(bf16x8*)(Bs + (byte >> 1)) = h;
    }
    __syncthreads();

    f32x4 acc[4][4] = {};
#pragma unroll
    for (int ks = 0; ks < 4; ++ks) {
      bf16x8 a[4], b[4];
#pragma unroll
      for (int mi = 0; mi < 4; ++mi) {
        int row = wm * 64 + mi * 16 + (lane & 15);
        int byte = (row * 256 + ks * 64 + ((lane >> 4) << 4)) ^ ((row & 7) << 4);
        a[mi] = *(const bf16x8*)(As + (byte >> 1));
      }
#pragma unroll
      for (int ni = 0; ni < 4; ++ni) {
        int n = wn * 64 + ni * 16 + (lane & 15);
        int byte = (n * 256 + ks * 64 + ((lane >> 4) << 4)) ^ ((n & 7) << 4);
        b[ni] = *(const bf16x8*)(Bs + (byte >> 1));
      }
#pragma unroll
      for (int mi = 0; mi < 4; ++mi)
#pragma unroll
        for (int ni = 0; ni < 4; ++ni)
          acc[mi][ni] =
              __builtin_amdgcn_mfma_f32_16x16x32_bf16(a[mi], b[ni], acc[mi][ni], 0, 0, 0);
    }

#pragma unroll
    for (int mi = 0; mi < 4; ++mi) {
      int rbase = row0 + wm * 64 + mi * 16 + ((lane >> 4) << 2);
#pragma unroll
      for (int ni = 0; ni < 4; ++ni) {
        int gcol = ct * 128 + wn * 64 + ni * 16 + (lane & 15);
        float bv = bias ? bias[gcol] : 0.f;
#pragma unroll
        for (int r = 0; r < 4; ++r) {
          int grow = rbase + r;
          if (grow < M) {
            float xv = acc[mi][ni][r] + bv;
            if (act) xv = silu_f(xv);
            C[(size_t)grow * Nn + gcol] = xv;
          }
        }
      }
    }
  }
}

// ---------------- vec_dot reduce ----------------
__global__ __launch_bounds__(256) void vecdot_kernel(const float* __restrict__ t12,
                                                     float* __restrict__ vdot, int n_nodes) {
  int n = blockIdx.x * 2 + (threadIdx.x >> 7);
  int h = threadIdx.x & 127;
  if (n >= n_nodes) return;
  const float* base = t12 + (size_t)n * 8 * 256;
  float acc = 0.f;
#pragma unroll
  for (int l = 0; l < 8; l++) acc += base[l * 256 + h] * base[l * 256 + 128 + h];
  vdot[(size_t)n * H + h] = acc;
}

// ---------------- message: attn + vm per edge ----------------
__global__ __launch_bounds__(256) void msg_kernel(const float* __restrict__ qkv,
                                                  const float* __restrict__ dkdv,
                                                  const float* __restrict__ r_ij,
                                                  const int* __restrict__ ei,
                                                  float* __restrict__ vm) {
  int e = blockIdx.x * 2 + (threadIdx.x >> 7);
  int h = threadIdx.x & 127;
  int src = ei[e], dst = ei[N_EDGES + e];
  float qv = qkv[(size_t)dst * 384 + h];
  float kv = qkv[(size_t)src * 384 + 128 + h];
  float vv = qkv[(size_t)src * 384 + 256 + h];
  float t = qv * kv * dkdv[(size_t)e * 256 + h];
#pragma unroll
  for (int off = 8; off >= 1; off >>= 1) t += __shfl_xor(t, off, 16);
  float r = r_ij[e];
  float cut = 0.5f * (__cosf(0.6283185307f * r) + 1.f);
  cut = (r < 5.f) ? cut : 0.f;
  float attn = silu_f(t) * cut;
  vm[(size_t)e * H + h] = vv * dkdv[(size_t)e * 256 + 128 + h] * attn;
}

// ---------------- CSR build: histogram, scan, fill ----------------
__global__ __launch_bounds__(256) void hist_kernel(const int* __restrict__ ei,
                                                   int* __restrict__ cnt) {
  int e = blockIdx.x * 256 + threadIdx.x;
  if (e < N_EDGES) atomicAdd(&cnt[ei[N_EDGES + e]], 1);
}

__global__ __launch_bounds__(1024) void scan_kernel(const int* __restrict__ cnt,
                                                    int* __restrict__ rowptr) {
  __shared__ int wsum[16];
  int t = threadIdx.x;
  int base = t * 10;
  int local[10];
  int s = 0;
#pragma unroll
  for (int i = 0; i < 10; ++i) {
    int v = (base + i < N_NODES) ? cnt[base + i] : 0;
    local[i] = s;
    s += v;
  }
  int lane = t & 63, wave = t >> 6;
  int inc = s;
#pragma unroll
  for (int off = 1; off < 64; off <<= 1) {
    int u = __shfl_up(inc, off, 64);
    if (lane >= off) inc += u;
  }
  if (lane == 63) wsum[wave] = inc;
  __syncthreads();
  if (t == 0) {
    int acc = 0;
#pragma unroll
    for (int w = 0; w < 16; ++w) { int v = wsum[w]; wsum[w] = acc; acc += v; }
  }
  __syncthreads();
  int excl = inc - s + wsum[wave];
#pragma unroll
  for (int i = 0; i < 10; ++i)
    if (base + i <= N_NODES) rowptr[base + i] = excl + local[i];
}

__global__ __launch_bounds__(256) void fill_kernel(const int* __restrict__ ei,
                                                   const int* __restrict__ rowptr,
                                                   int* __restrict__ cursor,
                                                   int* __restrict__ elist) {
  int e = blockIdx.x * 256 + threadIdx.x;
  if (e < N_EDGES) {
    int d = ei[N_EDGES + e];
    int p = atomicAdd(&cursor[d], 1);
    elist[rowptr[d] + p] = e;
  }
}

// ---------------- gather: x_agg = Σ vm ; dvec = Σ vec_m (no atomics) ----------------
__global__ __launch_bounds__(256) void gather_kernel(const float* __restrict__ vm,
                                                     const float* __restrict__ s,
                                                     const float* __restrict__ vecw,
                                                     const float* __restrict__ d_ij,
                                                     const int* __restrict__ ei,
                                                     const int* __restrict__ rowptr,
                                                     const int* __restrict__ elist,
                                                     float* __restrict__ x_agg,
                                                     float* __restrict__ dvec) {
  int n = blockIdx.x * 2 + (threadIdx.x >> 7);
  int h = threadIdx.x & 127;
  if (n >= N_NODES) return;
  int beg = rowptr[n], end = rowptr[n + 1];
  float ax = 0.f;
  float av[L] = {};
  for (int p = beg; p < end; ++p) {
    int e = elist[p];
    int src = ei[e];
    ax += vm[(size_t)e * H + h];
    float s1 = s[(size_t)e * 256 + h];
    float s2 = s[(size_t)e * 256 + 128 + h];
    const float* vrow = vecw + (size_t)src * L * H + h;
    const float* dd = d_ij + (size_t)e * L;
#pragma unroll
    for (int l = 0; l < L; l++) av[l] += vrow[l * H] * s1 + s2 * dd[l];
  }
  x_agg[(size_t)n * H + h] = ax;
  float* drow = dvec + (size_t)n * L * H + h;
#pragma unroll
  for (int l = 0; l < L; l++) drow[l * H] = av[l];
}

// ---------------- edge update (vtvs: [NL][256] = vt|vs) ----------------
__global__ __launch_bounds__(256) void edgeupd_kernel(const float* __restrict__ vtvs,
                                                      const float* __restrict__ d_ij,
                                                      const float* __restrict__ dfw,
                                                      const int* __restrict__ ei,
                                                      float* __restrict__ df) {
  int e = blockIdx.x * 2 + (threadIdx.x >> 7);
  int h = threadIdx.x & 127;
  int src = ei[e], dst = ei[N_EDGES + e];
  float d[L];
  float sd2 = 0.f;
#pragma unroll
  for (int l = 0; l < L; l++) {
    d[l] = d_ij[(size_t)e * L + l];
    sd2 += d[l] * d[l];
  }
  const float* arow = vtvs + (size_t)dst * L * 256 + h;
  const float* brow = vtvs + (size_t)src * L * 256 + 128 + h;
  float dot = 0.f, p1 = 0.f, p2 = 0.f;
#pragma unroll
  for (int l = 0; l < L; l++) {
    float a = arow[l * 256], bb = brow[l * 256];
    dot += a * bb;
    p1 += a * d[l];
    p2 += bb * d[l];
  }
  float wdot = dot - p1 * p2 * (2.f - sd2);
  df[(size_t)e * H + h] = dfw[(size_t)e * H + h] * wdot;
}

// ---------------- final node update ----------------
__global__ __launch_bounds__(256) void final_kernel(const float* __restrict__ o,
                                                    const float* __restrict__ vdot,
                                                    const float* __restrict__ vec3,
                                                    float* __restrict__ dx,
                                                    float* __restrict__ dvec, int n_nodes) {
  int n = blockIdx.x * 2 + (threadIdx.x >> 7);
  int h = threadIdx.x & 127;
  if (n >= n_nodes) return;
  float o1 = o[(size_t)n * 384 + h];
  float o2 = o[(size_t)n * 384 + 128 + h];
  float o3 = o[(size_t)n * 384 + 256 + h];
  dx[(size_t)n * H + h] = vdot[(size_t)n * H + h] * o2 + o3;
  float* drow = dvec + (size_t)n * L * H + h;
  const float* v3 = vec3 + (size_t)n * L * H + h;
#pragma unroll
  for (int l = 0; l < L; l++) drow[l * H] += v3[l * H] * o1;
}

extern "C" void kernel_launch(void* const* d_in, const int* in_sizes, int n_in, void* d_out,
                              int out_size, void* d_ws, size_t ws_size, hipStream_t stream) {
  const float* x = (const float*)d_in[0];
  const float* vec = (const float*)d_in[1];
  const float* f_ij = (const float*)d_in[2];
  const float* d_ij = (const float*)d_in[3];
  const float* r_ij = (const float*)d_in[4];
  const int* ei = (const int*)d_in[5];
  const float* ln_g = (const float*)d_in[6];
  const float* ln_b = (const float*)d_in[7];
  const float* vln_w = (const float*)d_in[8];
  const float* W_vec = (const float*)d_in[9];
  const float* W_q = (const float*)d_in[10];
  const float* b_q = (const float*)d_in[11];
  const float* W_k = (const float*)d_in[12];
  const float* b_k = (const float*)d_in[13];
  const float* W_v = (const float*)d_in[14];
  const float* b_v = (const float*)d_in[15];
  const float* W_dk = (const float*)d_in[16];
  const float* b_dk = (const float*)d_in[17];
  const float* W_dv = (const float*)d_in[18];
  const float* b_dv = (const float*)d_in[19];
  const float* W_s = (const float*)d_in[20];
  const float* b_s = (const float*)d_in[21];
  const float* W_f = (const float*)d_in[22];
  const float* b_f = (const float*)d_in[23];
  const float* W_src = (const float*)d_in[24];
  const float* W_trg = (const float*)d_in[25];
  const float* W_o = (const float*)d_in[26];
  const float* b_o = (const float*)d_in[27];

  float* out = (float*)d_out;
  float* dx = out;
  float* dvec = out + (size_t)N_NODES * H;
  float* df = dvec + (size_t)N_NODES * L * H;

  // ---- workspace plan (timeshared) ----
  float* ws = (float*)d_ws;
  float* E = ws;                       // 20,480,000: t12 -> qkv -> vtvs -> o
  float* Cg = ws + 20480000;           // 16,384,000: dkdv -> s
  float* vecw = ws + 36864000;         // 10,240,000
  float* vec3 = ws + 47104000;         // 10,240,000
  float* D = ws + 57344000;            //  8,192,000: vm -> dfw
  float* xln = ws + 65536000;          //  1,280,000: xln -> x_agg
  float* vdot = ws + 66816000;         //  1,280,000
  __bf16* Wt = (__bf16*)(ws + 68096000);  // 262,144 bf16 = 131,072 f32 slots
  float* bqkv = ws + 68096000 + 131072;   // 384
  float* bdkdv = bqkv + 384;              // 256
  int* rowptr = (int*)(bdkdv + 256);      // 10,001
  int* elist = rowptr + 10001;            // 64,000
  int* cnt = elist + 64000;               // 10,000
  int* cursor = cnt + 10000;              // 10,000

  float* t12 = E;
  float* qkv = E;
  float* vtvs = E;
  float* o_buf = E;
  float* dkdv = Cg;
  float* s_buf = Cg;
  float* vm = D;
  float* dfw = D;
  float* x_agg = xln;

  dim3 b256(256);

  // CSR build (depends only on ei)
  hipMemsetAsync(cnt, 0, N_NODES * sizeof(int), stream);
  hipMemsetAsync(cursor, 0, N_NODES * sizeof(int), stream);
  hist_kernel<<<dim3((N_EDGES + 255) / 256), b256, 0, stream>>>(ei, cnt);
  scan_kernel<<<dim3(1), dim3(1024), 0, stream>>>(cnt, rowptr);
  fill_kernel<<<dim3((N_EDGES + 255) / 256), b256, 0, stream>>>(ei, rowptr, cursor, elist);

  // 0. weight convert/transpose + bias concat
  wconv_kernel<<<dim3(258), b256, 0, stream>>>(W_vec, W_q, W_k, W_v, W_dk, W_dv, W_s, W_trg,
                                               W_src, W_f, W_o, b_q, b_k, b_v, b_dk, b_dv, Wt,
                                               bqkv, bdkdv);
  // 1. x_ln = layernorm(x)
  ln_kernel<<<dim3((N_NODES + 3) / 4), b256, 0, stream>>>(x, ln_g, ln_b, xln, N_NODES);
  // 2. vecw = vec * vln_w
  vecw_kernel<<<dim3(2048), b256, 0, stream>>>(vec, vln_w, vecw, (size_t)N_NODES * L * H);
  // 3. t12 = vecw @ W_vec[:,0:256]
  gemm_bf16<<<dim3(625), b256, 0, stream>>>(vecw, Wt + 0, nullptr, t12, NL, 256, 0);
  // 4. vec3 = vecw @ W_vec[:,256:384]
  gemm_bf16<<<dim3(625), b256, 0, stream>>>(vecw, Wt + 32768, nullptr, vec3, NL, 128, 0);
  // 5. vec_dot
  vecdot_kernel<<<dim3(5000), b256, 0, stream>>>(t12, vdot, N_NODES);
  // 6. qkv = xln @ [Wq|Wk|Wv] + b   (overwrites t12: consumed in 5)
  gemm_bf16<<<dim3(79), b256, 0, stream>>>(xln, Wt + 49152, bqkv, qkv, N_NODES, 384, 0);
  // 7. dkdv = silu(f_ij @ [Wdk|Wdv] + b)
  gemm_bf16<<<dim3(500), b256, 0, stream>>>(f_ij, Wt + 98304, bdkdv, dkdv, N_EDGES, 256, 1);
  // 8. message -> vm
  msg_kernel<<<dim3(N_EDGES / 2), b256, 0, stream>>>(qkv, dkdv, r_ij, ei, vm);
  // 9. s = silu(vm @ W_s + b)   (overwrites dkdv: consumed in 8)
  gemm_bf16<<<dim3(500), b256, 0, stream>>>(vm, Wt + 131072, b_s, s_buf, N_EDGES, 256, 1);
  // 10. gather into x_agg and dvec (no atomics)
  gather_kernel<<<dim3(N_NODES / 2), b256, 0, stream>>>(vm, s_buf, vecw, d_ij, ei, rowptr,
                                                        elist, x_agg, dvec);
  // 11. vtvs = vecw @ [W_trg|W_src]   (overwrites qkv: consumed in 8)
  gemm_bf16<<<dim3(625), b256, 0, stream>>>(vecw, Wt + 163840, nullptr, vtvs, NL, 256, 0);
  // 12. dfw = silu(f_ij @ W_f + b)   (overwrites vm: consumed in 9,10)
  gemm_bf16<<<dim3(500), b256, 0, stream>>>(f_ij, Wt + 196608, b_f, dfw, N_EDGES, 128, 1);
  // 13. edge update -> df
  edgeupd_kernel<<<dim3(N_EDGES / 2), b256, 0, stream>>>(vtvs, d_ij, dfw, ei, df);
  // 14. o = x_agg @ W_o + b   (overwrites vtvs: consumed in 13)
  gemm_bf16<<<dim3(79), b256, 0, stream>>>(x_agg, Wt + 212992, b_o, o_buf, N_NODES, 384, 0);
  // 15. final: dx, dvec += vec3*o1
  final_kernel<<<dim3(5000), b256, 0, stream>>>(o_buf, vdot, vec3, dx, dvec, N_NODES);
}

// Round 4
// 472.855 us; speedup vs baseline: 2.5032x; 1.2000x over previous
//
#include <hip/hip_runtime.h>
#include <hip/hip_bf16.h>
#include <math.h>

#define N_NODES 10000
#define N_EDGES 64000
#define H 128
#define L 8
#define NL (N_NODES * L)

typedef __attribute__((ext_vector_type(4))) float f32x4;
typedef __attribute__((ext_vector_type(8))) __bf16 bf16x8;

__device__ __forceinline__ float silu_f(float x) { return x / (1.f + __expf(-x)); }

// ---------------- LayerNorm: one wave per node ----------------
__global__ __launch_bounds__(256) void ln_kernel(const float* __restrict__ x,
                                                 const float* __restrict__ g,
                                                 const float* __restrict__ b,
                                                 float* __restrict__ out, int n_nodes) {
  int wave = threadIdx.x >> 6;
  int lane = threadIdx.x & 63;
  int n = blockIdx.x * 4 + wave;
  if (n >= n_nodes) return;
  const float* xr = x + (size_t)n * H;
  float a0 = xr[lane], a1 = xr[lane + 64];
  float s = a0 + a1;
#pragma unroll
  for (int off = 32; off >= 1; off >>= 1) s += __shfl_xor(s, off, 64);
  float mu = s * (1.f / H);
  float d0 = a0 - mu, d1 = a1 - mu;
  float v = d0 * d0 + d1 * d1;
#pragma unroll
  for (int off = 32; off >= 1; off >>= 1) v += __shfl_xor(v, off, 64);
  float rstd = rsqrtf(v * (1.f / H) + 1e-5f);
  float* orow = out + (size_t)n * H;
  orow[lane] = d0 * rstd * g[lane] + b[lane];
  orow[lane + 64] = d1 * rstd * g[lane + 64] + b[lane + 64];
}

// ---------------- vecw = vec * vln_w  -> bf16 ----------------
__global__ __launch_bounds__(256) void vecw_kernel(const float* __restrict__ vec,
                                                   const float* __restrict__ w,
                                                   __bf16* __restrict__ out, size_t total8) {
  size_t i = (size_t)blockIdx.x * blockDim.x + threadIdx.x;
  size_t stride = (size_t)gridDim.x * blockDim.x;
  for (; i < total8; i += stride) {
    size_t base = i * 8;
    f32x4 a = *(const f32x4*)(vec + base);
    f32x4 b = *(const f32x4*)(vec + base + 4);
    int c = (int)(base & 127);
    bf16x8 h;
    h[0] = (__bf16)(a[0] * w[c + 0]); h[1] = (__bf16)(a[1] * w[c + 1]);
    h[2] = (__bf16)(a[2] * w[c + 2]); h[3] = (__bf16)(a[3] * w[c + 3]);
    h[4] = (__bf16)(b[0] * w[c + 4]); h[5] = (__bf16)(b[1] * w[c + 5]);
    h[6] = (__bf16)(b[2] * w[c + 6]); h[7] = (__bf16)(b[3] * w[c + 7]);
    *(bf16x8*)(out + base) = h;
  }
}

// ---------------- weight convert: f32 [128][nc] -> bf16 [nc][128], + bias concat ----------------
__global__ __launch_bounds__(256) void wconv_kernel(
    const float* __restrict__ Wvec, const float* __restrict__ Wq, const float* __restrict__ Wk,
    const float* __restrict__ Wv, const float* __restrict__ Wdk, const float* __restrict__ Wdv,
    const float* __restrict__ Ws, const float* __restrict__ Wtrg, const float* __restrict__ Wsrc,
    const float* __restrict__ Wf, const float* __restrict__ Wo,
    const float* __restrict__ bq, const float* __restrict__ bk, const float* __restrict__ bv,
    const float* __restrict__ bdk, const float* __restrict__ bdv,
    __bf16* __restrict__ Wt, float* __restrict__ bqkv, float* __restrict__ bdkdv) {
  int bid = blockIdx.x;
  int t = threadIdx.x;
  if (bid >= 256) {
    if (bid == 256) {
      if (t < 128) { bqkv[t] = bq[t]; bqkv[128 + t] = bk[t]; bqkv[256 + t] = bv[t]; }
    } else {
      if (t < 128) { bdkdv[t] = bdk[t]; bdkdv[128 + t] = bdv[t]; }
    }
    return;
  }
  const float* W; int ldw, dst, tb;
  if      (bid < 48)  { W = Wvec; ldw = 384; dst = 0;      tb = 0;   }
  else if (bid < 64)  { W = Wq;   ldw = 128; dst = 49152;  tb = 48;  }
  else if (bid < 80)  { W = Wk;   ldw = 128; dst = 65536;  tb = 64;  }
  else if (bid < 96)  { W = Wv;   ldw = 128; dst = 81920;  tb = 80;  }
  else if (bid < 112) { W = Wdk;  ldw = 128; dst = 98304;  tb = 96;  }
  else if (bid < 128) { W = Wdv;  ldw = 128; dst = 114688; tb = 112; }
  else if (bid < 160) { W = Ws;   ldw = 256; dst = 131072; tb = 128; }
  else if (bid < 176) { W = Wtrg; ldw = 128; dst = 163840; tb = 160; }
  else if (bid < 192) { W = Wsrc; ldw = 128; dst = 180224; tb = 176; }
  else if (bid < 208) { W = Wf;   ldw = 128; dst = 196608; tb = 192; }
  else                { W = Wo;   ldw = 384; dst = 212992; tb = 208; }
  int lt = bid - tb;
  int ctiles = ldw >> 5;
  int kt = lt / ctiles, ct = lt % ctiles;
  __shared__ float tile[32][33];
  int tx = t & 31, ty = t >> 5;
#pragma unroll
  for (int i = 0; i < 4; ++i)
    tile[ty + i * 8][tx] = W[(size_t)(kt * 32 + ty + i * 8) * ldw + ct * 32 + tx];
  __syncthreads();
#pragma unroll
  for (int i = 0; i < 4; ++i)
    Wt[dst + (size_t)(ct * 32 + ty + i * 8) * 128 + kt * 32 + tx] =
        (__bf16)tile[tx][ty + i * 8];
}

// ---------------- MFMA GEMM: C[M,Nn] = act(A[M,128] @ Bt^T + bias), AT/CT templated ----------------
template <typename AT, typename CT>
__global__ __launch_bounds__(256) void gemm_t(const AT* __restrict__ A,
                                              const __bf16* __restrict__ Bt,
                                              const float* __restrict__ bias,
                                              CT* __restrict__ C, int M, int Nn, int act) {
  __shared__ __bf16 As[128 * 128];
  __shared__ __bf16 Bs[128 * 128];
  const int tid = threadIdx.x;
  const int lane = tid & 63;
  const int wave = tid >> 6;
  const int wm = wave >> 1, wn = wave & 1;
  const int row0 = blockIdx.x * 128;

#pragma unroll
  for (int i = 0; i < 8; ++i) {
    int c = tid + i * 256;
    int row = c >> 4, k8 = c & 15;
    int gm = row0 + row;
    bf16x8 h = {};
    if (gm < M) {
      if constexpr (sizeof(AT) == 4) {
        f32x4 f0 = *(const f32x4*)(A + (size_t)gm * 128 + k8 * 8);
        f32x4 f1 = *(const f32x4*)(A + (size_t)gm * 128 + k8 * 8 + 4);
        h[0] = (__bf16)f0[0]; h[1] = (__bf16)f0[1]; h[2] = (__bf16)f0[2]; h[3] = (__bf16)f0[3];
        h[4] = (__bf16)f1[0]; h[5] = (__bf16)f1[1]; h[6] = (__bf16)f1[2]; h[7] = (__bf16)f1[3];
      } else {
        h = *(const bf16x8*)(A + (size_t)gm * 128 + k8 * 8);
      }
    }
    int byte = (row * 256 + k8 * 16) ^ ((row & 7) << 4);
    *(bf16x8*)(As + (byte >> 1)) = h;
  }

  const int ncTiles = Nn >> 7;
  for (int ct = 0; ct < ncTiles; ++ct) {
    __syncthreads();
#pragma unroll
    for (int i = 0; i < 8; ++i) {
      int c = tid + i * 256;
      int n = c >> 4, k8 = c & 15;
      bf16x8 h = *(const bf16x8*)(Bt + ((size_t)(ct * 128 + n) << 7) + k8 * 8);
      int byte = (n * 256 + k8 * 16) ^ ((n & 7) << 4);
      *(bf16x8*)(Bs + (byte >> 1)) = h;
    }
    __syncthreads();

    f32x4 acc[4][4] = {};
#pragma unroll
    for (int ks = 0; ks < 4; ++ks) {
      bf16x8 a[4], b[4];
#pragma unroll
      for (int mi = 0; mi < 4; ++mi) {
        int row = wm * 64 + mi * 16 + (lane & 15);
        int byte = (row * 256 + ks * 64 + ((lane >> 4) << 4)) ^ ((row & 7) << 4);
        a[mi] = *(const bf16x8*)(As + (byte >> 1));
      }
#pragma unroll
      for (int ni = 0; ni < 4; ++ni) {
        int n = wn * 64 + ni * 16 + (lane & 15);
        int byte = (n * 256 + ks * 64 + ((lane >> 4) << 4)) ^ ((n & 7) << 4);
        b[ni] = *(const bf16x8*)(Bs + (byte >> 1));
      }
#pragma unroll
      for (int mi = 0; mi < 4; ++mi)
#pragma unroll
        for (int ni = 0; ni < 4; ++ni)
          acc[mi][ni] =
              __builtin_amdgcn_mfma_f32_16x16x32_bf16(a[mi], b[ni], acc[mi][ni], 0, 0, 0);
    }

#pragma unroll
    for (int mi = 0; mi < 4; ++mi) {
      int rbase = row0 + wm * 64 + mi * 16 + ((lane >> 4) << 2);
#pragma unroll
      for (int ni = 0; ni < 4; ++ni) {
        int gcol = ct * 128 + wn * 64 + ni * 16 + (lane & 15);
        float bv = bias ? bias[gcol] : 0.f;
#pragma unroll
        for (int r = 0; r < 4; ++r) {
          int grow = rbase + r;
          if (grow < M) {
            float xv = acc[mi][ni][r] + bv;
            if (act) xv = silu_f(xv);
            C[(size_t)grow * Nn + gcol] = (CT)xv;
          }
        }
      }
    }
  }
}

// ---------------- vec_dot reduce (t12 bf16 [N][8][256]) ----------------
__global__ __launch_bounds__(256) void vecdot_kernel(const __bf16* __restrict__ t12,
                                                     float* __restrict__ vdot, int n_nodes) {
  int n = blockIdx.x * 2 + (threadIdx.x >> 7);
  int h = threadIdx.x & 127;
  if (n >= n_nodes) return;
  const __bf16* base = t12 + (size_t)n * 8 * 256;
  float acc = 0.f;
#pragma unroll
  for (int l = 0; l < 8; l++)
    acc += (float)base[l * 256 + h] * (float)base[l * 256 + 128 + h];
  vdot[(size_t)n * H + h] = acc;
}

// ---------------- message: attn + vm per edge ----------------
__global__ __launch_bounds__(256) void msg_kernel(const float* __restrict__ qkv,
                                                  const __bf16* __restrict__ dkdv,
                                                  const float* __restrict__ r_ij,
                                                  const int* __restrict__ ei,
                                                  __bf16* __restrict__ vm) {
  int e = blockIdx.x * 2 + (threadIdx.x >> 7);
  int h = threadIdx.x & 127;
  int src = ei[e], dst = ei[N_EDGES + e];
  float qv = qkv[(size_t)dst * 384 + h];
  float kv = qkv[(size_t)src * 384 + 128 + h];
  float vv = qkv[(size_t)src * 384 + 256 + h];
  float t = qv * kv * (float)dkdv[(size_t)e * 256 + h];
#pragma unroll
  for (int off = 8; off >= 1; off >>= 1) t += __shfl_xor(t, off, 16);
  float r = r_ij[e];
  float cut = 0.5f * (__cosf(0.6283185307f * r) + 1.f);
  cut = (r < 5.f) ? cut : 0.f;
  float attn = silu_f(t) * cut;
  vm[(size_t)e * H + h] = (__bf16)(vv * (float)dkdv[(size_t)e * 256 + 128 + h] * attn);
}

// ---------------- CSR build: histogram, scan, fill ----------------
__global__ __launch_bounds__(256) void hist_kernel(const int* __restrict__ ei,
                                                   int* __restrict__ cnt) {
  int e = blockIdx.x * 256 + threadIdx.x;
  if (e < N_EDGES) atomicAdd(&cnt[ei[N_EDGES + e]], 1);
}

__global__ __launch_bounds__(1024) void scan_kernel(const int* __restrict__ cnt,
                                                    int* __restrict__ rowptr) {
  __shared__ int wsum[16];
  int t = threadIdx.x;
  int base = t * 10;
  int local[10];
  int s = 0;
#pragma unroll
  for (int i = 0; i < 10; ++i) {
    int v = (base + i < N_NODES) ? cnt[base + i] : 0;
    local[i] = s;
    s += v;
  }
  int lane = t & 63, wave = t >> 6;
  int inc = s;
#pragma unroll
  for (int off = 1; off < 64; off <<= 1) {
    int u = __shfl_up(inc, off, 64);
    if (lane >= off) inc += u;
  }
  if (lane == 63) wsum[wave] = inc;
  __syncthreads();
  if (t == 0) {
    int acc = 0;
#pragma unroll
    for (int w = 0; w < 16; ++w) { int v = wsum[w]; wsum[w] = acc; acc += v; }
  }
  __syncthreads();
  int excl = inc - s + wsum[wave];
#pragma unroll
  for (int i = 0; i < 10; ++i)
    if (base + i <= N_NODES) rowptr[base + i] = excl + local[i];
}

__global__ __launch_bounds__(256) void fill_kernel(const int* __restrict__ ei,
                                                   const int* __restrict__ rowptr,
                                                   int* __restrict__ cursor,
                                                   int* __restrict__ elist) {
  int e = blockIdx.x * 256 + threadIdx.x;
  if (e < N_EDGES) {
    int d = ei[N_EDGES + e];
    int p = atomicAdd(&cursor[d], 1);
    elist[rowptr[d] + p] = e;
  }
}

// ---------------- gather: x_agg = Σ vm ; dvec = Σ vec_m (no atomics) ----------------
__global__ __launch_bounds__(256) void gather_kernel(const __bf16* __restrict__ vm,
                                                     const __bf16* __restrict__ s,
                                                     const __bf16* __restrict__ vecw,
                                                     const float* __restrict__ d_ij,
                                                     const int* __restrict__ ei,
                                                     const int* __restrict__ rowptr,
                                                     const int* __restrict__ elist,
                                                     float* __restrict__ x_agg,
                                                     float* __restrict__ dvec) {
  int n = blockIdx.x * 2 + (threadIdx.x >> 7);
  int h = threadIdx.x & 127;
  if (n >= N_NODES) return;
  int beg = rowptr[n], end = rowptr[n + 1];
  float ax = 0.f;
  float av[L] = {};
  for (int p = beg; p < end; ++p) {
    int e = elist[p];
    int src = ei[e];
    ax += (float)vm[(size_t)e * H + h];
    float s1 = (float)s[(size_t)e * 256 + h];
    float s2 = (float)s[(size_t)e * 256 + 128 + h];
    const __bf16* vrow = vecw + (size_t)src * L * H + h;
    const float* dd = d_ij + (size_t)e * L;
#pragma unroll
    for (int l = 0; l < L; l++) av[l] += (float)vrow[l * H] * s1 + s2 * dd[l];
  }
  x_agg[(size_t)n * H + h] = ax;
  float* drow = dvec + (size_t)n * L * H + h;
#pragma unroll
  for (int l = 0; l < L; l++) drow[l * H] = av[l];
}

// ---------------- edge update (vtvs bf16 [NL][256] = vt|vs) ----------------
__global__ __launch_bounds__(256) void edgeupd_kernel(const __bf16* __restrict__ vtvs,
                                                      const float* __restrict__ d_ij,
                                                      const __bf16* __restrict__ dfw,
                                                      const int* __restrict__ ei,
                                                      float* __restrict__ df) {
  int e = blockIdx.x * 2 + (threadIdx.x >> 7);
  int h = threadIdx.x & 127;
  int src = ei[e], dst = ei[N_EDGES + e];
  float d[L];
  float sd2 = 0.f;
#pragma unroll
  for (int l = 0; l < L; l++) {
    d[l] = d_ij[(size_t)e * L + l];
    sd2 += d[l] * d[l];
  }
  const __bf16* arow = vtvs + (size_t)dst * L * 256 + h;
  const __bf16* brow = vtvs + (size_t)src * L * 256 + 128 + h;
  float dot = 0.f, p1 = 0.f, p2 = 0.f;
#pragma unroll
  for (int l = 0; l < L; l++) {
    float a = (float)arow[l * 256], bb = (float)brow[l * 256];
    dot += a * bb;
    p1 += a * d[l];
    p2 += bb * d[l];
  }
  float wdot = dot - p1 * p2 * (2.f - sd2);
  df[(size_t)e * H + h] = (float)dfw[(size_t)e * H + h] * wdot;
}

// ---------------- final node update ----------------
__global__ __launch_bounds__(256) void final_kernel(const float* __restrict__ o,
                                                    const float* __restrict__ vdot,
                                                    const __bf16* __restrict__ vec3,
                                                    float* __restrict__ dx,
                                                    float* __restrict__ dvec, int n_nodes) {
  int n = blockIdx.x * 2 + (threadIdx.x >> 7);
  int h = threadIdx.x & 127;
  if (n >= n_nodes) return;
  float o1 = o[(size_t)n * 384 + h];
  float o2 = o[(size_t)n * 384 + 128 + h];
  float o3 = o[(size_t)n * 384 + 256 + h];
  dx[(size_t)n * H + h] = vdot[(size_t)n * H + h] * o2 + o3;
  float* drow = dvec + (size_t)n * L * H + h;
  const __bf16* v3 = vec3 + (size_t)n * L * H + h;
#pragma unroll
  for (int l = 0; l < L; l++) drow[l * H] += (float)v3[l * H] * o1;
}

extern "C" void kernel_launch(void* const* d_in, const int* in_sizes, int n_in, void* d_out,
                              int out_size, void* d_ws, size_t ws_size, hipStream_t stream) {
  const float* x = (const float*)d_in[0];
  const float* vec = (const float*)d_in[1];
  const float* f_ij = (const float*)d_in[2];
  const float* d_ij = (const float*)d_in[3];
  const float* r_ij = (const float*)d_in[4];
  const int* ei = (const int*)d_in[5];
  const float* ln_g = (const float*)d_in[6];
  const float* ln_b = (const float*)d_in[7];
  const float* vln_w = (const float*)d_in[8];
  const float* W_vec = (const float*)d_in[9];
  const float* W_q = (const float*)d_in[10];
  const float* b_q = (const float*)d_in[11];
  const float* W_k = (const float*)d_in[12];
  const float* b_k = (const float*)d_in[13];
  const float* W_v = (const float*)d_in[14];
  const float* b_v = (const float*)d_in[15];
  const float* W_dk = (const float*)d_in[16];
  const float* b_dk = (const float*)d_in[17];
  const float* W_dv = (const float*)d_in[18];
  const float* b_dv = (const float*)d_in[19];
  const float* W_s = (const float*)d_in[20];
  const float* b_s = (const float*)d_in[21];
  const float* W_f = (const float*)d_in[22];
  const float* b_f = (const float*)d_in[23];
  const float* W_src = (const float*)d_in[24];
  const float* W_trg = (const float*)d_in[25];
  const float* W_o = (const float*)d_in[26];
  const float* b_o = (const float*)d_in[27];

  float* out = (float*)d_out;
  float* dx = out;
  float* dvec = out + (size_t)N_NODES * H;
  float* df = dvec + (size_t)N_NODES * L * H;

  // ---- workspace plan (~142 MB, timeshared; offsets in f32 slots) ----
  float* ws = (float*)d_ws;
  float* E = ws;                        // 10,240,000: t12(bf16) -> qkv(f32) -> vtvs(bf16) -> o(f32)
  float* Cg = ws + 10240000;            //  8,192,000: dkdv(bf16) -> s(bf16)
  __bf16* vecw = (__bf16*)(ws + 18432000);   // 10,240,000 bf16
  __bf16* vec3 = (__bf16*)(ws + 23552000);   // 10,240,000 bf16
  __bf16* D = (__bf16*)(ws + 28672000);      //  8,192,000 bf16: vm -> dfw
  float* xln = ws + 32768000;           //  1,280,000: xln -> x_agg
  float* vdot = ws + 34048000;          //  1,280,000
  __bf16* Wt = (__bf16*)(ws + 35328000);     // 262,144 bf16
  float* bqkv = ws + 35328000 + 131072;
  float* bdkdv = bqkv + 384;
  int* rowptr = (int*)(bdkdv + 256);    // 10,001
  int* elist = rowptr + 10001;          // 64,000
  int* cnt = elist + 64000;             // 10,000
  int* cursor = cnt + 10000;            // 10,000

  __bf16* t12 = (__bf16*)E;
  float* qkv = E;
  __bf16* vtvs = (__bf16*)E;
  float* o_buf = E;
  __bf16* dkdv = (__bf16*)Cg;
  __bf16* s_buf = (__bf16*)Cg;
  __bf16* vm = D;
  __bf16* dfw = D;
  float* x_agg = xln;

  dim3 b256(256);

  // CSR build (depends only on ei)
  hipMemsetAsync(cnt, 0, N_NODES * sizeof(int), stream);
  hipMemsetAsync(cursor, 0, N_NODES * sizeof(int), stream);
  hist_kernel<<<dim3((N_EDGES + 255) / 256), b256, 0, stream>>>(ei, cnt);
  scan_kernel<<<dim3(1), dim3(1024), 0, stream>>>(cnt, rowptr);
  fill_kernel<<<dim3((N_EDGES + 255) / 256), b256, 0, stream>>>(ei, rowptr, cursor, elist);

  // 0. weight convert/transpose + bias concat
  wconv_kernel<<<dim3(258), b256, 0, stream>>>(W_vec, W_q, W_k, W_v, W_dk, W_dv, W_s, W_trg,
                                               W_src, W_f, W_o, b_q, b_k, b_v, b_dk, b_dv, Wt,
                                               bqkv, bdkdv);
  // 1. x_ln = layernorm(x)
  ln_kernel<<<dim3((N_NODES + 3) / 4), b256, 0, stream>>>(x, ln_g, ln_b, xln, N_NODES);
  // 2. vecw = vec * vln_w (bf16)
  vecw_kernel<<<dim3(2048), b256, 0, stream>>>(vec, vln_w, vecw, (size_t)NL * H / 8);
  // 3. t12 = vecw @ W_vec[:,0:256] (bf16 out)
  gemm_t<__bf16, __bf16><<<dim3(625), b256, 0, stream>>>(vecw, Wt + 0, nullptr, t12, NL, 256, 0);
  // 4. vec3 = vecw @ W_vec[:,256:384] (bf16 out)
  gemm_t<__bf16, __bf16><<<dim3(625), b256, 0, stream>>>(vecw, Wt + 32768, nullptr, vec3, NL, 128, 0);
  // 5. vec_dot
  vecdot_kernel<<<dim3(5000), b256, 0, stream>>>(t12, vdot, N_NODES);
  // 6. qkv = xln @ [Wq|Wk|Wv] + b (f32 out; overwrites t12: consumed in 5)
  gemm_t<float, float><<<dim3(79), b256, 0, stream>>>(xln, Wt + 49152, bqkv, qkv, N_NODES, 384, 0);
  // 7. dkdv = silu(f_ij @ [Wdk|Wdv] + b) (bf16 out)
  gemm_t<float, __bf16><<<dim3(500), b256, 0, stream>>>(f_ij, Wt + 98304, bdkdv, dkdv, N_EDGES, 256, 1);
  // 8. message -> vm (bf16)
  msg_kernel<<<dim3(N_EDGES / 2), b256, 0, stream>>>(qkv, dkdv, r_ij, ei, vm);
  // 9. s = silu(vm @ W_s + b) (bf16; overwrites dkdv: consumed in 8)
  gemm_t<__bf16, __bf16><<<dim3(500), b256, 0, stream>>>(vm, Wt + 131072, b_s, s_buf, N_EDGES, 256, 1);
  // 10. gather into x_agg and dvec (no atomics)
  gather_kernel<<<dim3(N_NODES / 2), b256, 0, stream>>>(vm, s_buf, vecw, d_ij, ei, rowptr,
                                                        elist, x_agg, dvec);
  // 11. vtvs = vecw @ [W_trg|W_src] (bf16; overwrites qkv: consumed in 8)
  gemm_t<__bf16, __bf16><<<dim3(625), b256, 0, stream>>>(vecw, Wt + 163840, nullptr, vtvs, NL, 256, 0);
  // 12. dfw = silu(f_ij @ W_f + b) (bf16; overwrites vm: consumed in 9,10)
  gemm_t<float, __bf16><<<dim3(500), b256, 0, stream>>>(f_ij, Wt + 196608, b_f, dfw, N_EDGES, 128, 1);
  // 13. edge update -> df
  edgeupd_kernel<<<dim3(N_EDGES / 2), b256, 0, stream>>>(vtvs, d_ij, dfw, ei, df);
  // 14. o = x_agg @ W_o + b (f32; overwrites vtvs: consumed in 13)
  gemm_t<float, float><<<dim3(79), b256, 0, stream>>>(x_agg, Wt + 212992, b_o, o_buf, N_NODES, 384, 0);
  // 15. final: dx, dvec += vec3*o1
  final_kernel<<<dim3(5000), b256, 0, stream>>>(o_buf, vdot, vec3, dx, dvec, N_NODES);
}